// Round 10
// baseline (1612.558 us; speedup 1.0000x reference)
//
#include <hip/hip_runtime.h>
#include <hip/hip_bf16.h>
#include <cstdint>
#include <cstddef>

#define TNUM 8192
#define DDIM 2048
#define FDIM 4096
#define NEXP 8

typedef __attribute__((ext_vector_type(4))) float f32x4;
typedef __attribute__((ext_vector_type(4))) unsigned u32x4;
typedef __attribute__((ext_vector_type(8))) short s16x8;
typedef __attribute__((ext_vector_type(8))) __bf16 bf16x8v;

__device__ inline f32x4 mfma16(s16x8 a, s16x8 b, f32x4 c) {
  return __builtin_amdgcn_mfma_f32_16x16x32_bf16(
      __builtin_bit_cast(bf16x8v, a), __builtin_bit_cast(bf16x8v, b), c, 0, 0, 0);
}

__device__ inline unsigned short bf16r(float f) {
  union { float f; unsigned u; } x; x.f = f;
  unsigned r = x.u + 0x7fffu + ((x.u >> 16) & 1u);
  return (unsigned short)(r >> 16);
}

__device__ inline unsigned pk2(float a, float b) {
  __hip_bfloat162 h = __float22bfloat162_rn(make_float2(a, b));
  unsigned r;
  __builtin_memcpy(&r, &h, 4);
  return r;
}

// XOR swizzle within 128-byte rows: bijective per row, same fn on write+read
__device__ inline int swz16(int row, int b) {
  return (row << 7) + (b ^ ((row & 7) << 4));
}

typedef const __attribute__((address_space(1))) void* gp_t;
typedef __attribute__((address_space(3))) void* lp_t;
__device__ inline void gl16(const void* g, void* l) {
  __builtin_amdgcn_global_load_lds((gp_t)g, (lp_t)l, 16, 0, 0);
}

#define FENCE asm volatile("" ::: "memory")

// ---------------- router: fp64 logits, top-2 on logits, fp32 softmax values --
__global__ __launch_bounds__(256) void k_router(
    const float* __restrict__ x, const float* __restrict__ gw,
    int* __restrict__ top_idx, float* __restrict__ top_w, int* __restrict__ counts) {
  __shared__ float gwT[NEXP][DDIM];
  const int tid = threadIdx.x;
  for (int i = tid; i < NEXP * DDIM; i += 256) {
    int d = i >> 3, e = i & 7;
    gwT[e][d] = gw[i];
  }
  __syncthreads();
  const int lane = tid & 63;
  const int t = blockIdx.x * 4 + (tid >> 6);
  const float4* xr = (const float4*)(x + (size_t)t * DDIM);
  double acc[NEXP];
#pragma unroll
  for (int e = 0; e < NEXP; e++) acc[e] = 0.0;
  for (int d4 = lane; d4 < DDIM / 4; d4 += 64) {
    float4 xv = xr[d4];
#pragma unroll
    for (int e = 0; e < NEXP; e++) {
      float4 gv = *(const float4*)&gwT[e][d4 * 4];
      acc[e] += (double)xv.x * gv.x + (double)xv.y * gv.y +
                (double)xv.z * gv.z + (double)xv.w * gv.w;
    }
  }
#pragma unroll
  for (int e = 0; e < NEXP; e++) {
    double v = acc[e];
#pragma unroll
    for (int s = 32; s > 0; s >>= 1) v += __shfl_xor(v, s);
    acc[e] = v;
  }
  if (lane == 0) {
    int i0 = 0; double b0 = acc[0];
#pragma unroll
    for (int e = 1; e < NEXP; e++) if (acc[e] > b0) { b0 = acc[e]; i0 = e; }
    int i1 = (i0 == 0) ? 1 : 0; double b1 = acc[i1];
#pragma unroll
    for (int e = 0; e < NEXP; e++) {
      if (e == i0 || e == i1) continue;
      if (acc[e] > b1) { b1 = acc[e]; i1 = e; }
    }
    float lc[NEXP]; float mx = -1e30f;
#pragma unroll
    for (int e = 0; e < NEXP; e++) {
      lc[e] = tanhf((float)(acc[e] * (1.0 / 30.0))) * 30.0f;
      mx = lc[e] > mx ? lc[e] : mx;
    }
    float s = 0.0f;
#pragma unroll
    for (int e = 0; e < NEXP; e++) { lc[e] = expf(lc[e] - mx); s += lc[e]; }
    float inv = 1.0f / s;
    top_idx[t * 2] = i0; top_idx[t * 2 + 1] = i1;
    top_w[t * 2] = lc[i0] * inv; top_w[t * 2 + 1] = lc[i1] * inv;
    atomicAdd(&counts[i0], 1);
    atomicAdd(&counts[i1], 1);
  }
}

__global__ void k_scan(const int* __restrict__ counts, int* __restrict__ offs,
                       int* __restrict__ cursor) {
  if (threadIdx.x == 0) {
    int s = 0;
    for (int e = 0; e < NEXP; e++) { offs[e] = s; cursor[e] = s; s += counts[e]; }
    offs[NEXP] = s;
  }
}

__global__ void k_scatter(const int* __restrict__ top_idx, const float* __restrict__ top_w,
                          int* __restrict__ cursor, int* __restrict__ perm_tok,
                          float* __restrict__ perm_w) {
  int t = blockIdx.x * 256 + threadIdx.x;
#pragma unroll
  for (int k = 0; k < 2; k++) {
    int e = top_idx[t * 2 + k];
    int pos = atomicAdd(&cursor[e], 1);
    perm_tok[pos] = t;
    perm_w[pos] = top_w[t * 2 + k];
  }
}

__global__ void k_cast(const float* __restrict__ x, unsigned short* __restrict__ xb) {
  size_t i = ((size_t)blockIdx.x * 256 + threadIdx.x) * 8;
  f32x4 a = *(const f32x4*)(x + i);
  f32x4 b = *(const f32x4*)(x + i + 4);
  u32x4 v;
  v[0] = pk2(a[0], a[1]); v[1] = pk2(a[2], a[3]);
  v[2] = pk2(b[0], b[1]); v[3] = pk2(b[2], b[3]);
  *(u32x4*)(xb + i) = v;
}

// ---- one-shot: fp32 [E][K][N] -> bf16 [E][n'][K] transpose+convert ----------
// cmap=0: n'=n. cmap=1 (gate): n'=((n>>4)<<5)+(n&15). cmap=2 (up): +16.
__global__ __launch_bounds__(256) void k_convT(
    const float* __restrict__ src, unsigned short* __restrict__ dst,
    int K, int N, int cmap) {
  __shared__ char ct[8192];
  const int e = blockIdx.z;
  const float* src_e = src + (size_t)e * K * N;
  const int nout = cmap ? 2 * N : N;
  unsigned short* dst_e = dst + (size_t)e * nout * K;
  const int k0 = blockIdx.y * 64, n0 = blockIdx.x * 64;
  const int tid = threadIdx.x;
#pragma unroll
  for (int i = 0; i < 4; i++) {
    int idx = tid + i * 256;
    int kr = idx >> 4, f4 = idx & 15;
    f32x4 v = *(const f32x4*)(src_e + (size_t)(k0 + kr) * N + n0 + f4 * 4);
#pragma unroll
    for (int j = 0; j < 4; j++) {
      int n = f4 * 4 + j;
      *(unsigned short*)(ct + n * 128 + ((kr * 2) ^ ((n & 7) << 4))) = bf16r(v[j]);
    }
  }
  __syncthreads();
#pragma unroll
  for (int i = 0; i < 2; i++) {
    int s = tid + i * 256;
    int n = s >> 3, ks = s & 7;
    int gn = n0 + n;
    int cd = cmap ? (((gn >> 4) << 5) + (gn & 15) + (cmap == 2 ? 16 : 0)) : gn;
    s16x8 val = *(const s16x8*)(ct + n * 128 + ((ks * 16) ^ ((n & 7) << 4)));
    *(s16x8*)(dst_e + (size_t)cd * K + k0 + ks * 8) = val;
  }
}

// Stage quarter-tile U (0=Alo,1=Ahi,2=Blo,3=Bhi) of K-tile TN into buf TN&1.
#define STAGEU(U, TN)                                                          \
  {                                                                            \
    char* db_ = lds + ((TN) & 1) * 65536 + (U) * 16384 + wid * 2048;           \
    gl16(sp[U][0] + (size_t)(TN) * 64, db_);                                   \
    gl16(sp[U][1] + (size_t)(TN) * 64, db_ + 1024);                            \
  }

#define VMC(N) asm volatile("s_waitcnt vmcnt(" #N ")" ::: "memory")

// One pipelined phase: ds-read frags for quadrant (MIH,NIH) of tile t (buf),
// issue stage of quarter U of tile t+1, barrier (absorbs read latency),
// then dense setprio-protected MFMA on registers.
// Correctness: reads of tile t are sealed by the boundary barrier (RAW via
// per-wave vmcnt(0)-before-barrier); MFMAs touch no LDS; stage targets buf^1
// whose readers finished before the previous boundary barrier (WAR).
#define PH(MIH, NIH, U)                                                        \
  {                                                                            \
    char* Ab_ = lds + buf * 65536;                                             \
    char* Bb_ = Ab_ + 32768;                                                   \
    s16x8 a0_[4], a1_[4];                                                      \
    _Pragma("unroll") for (int mi = 0; mi < 4; mi++) {                         \
      a0_[mi] = *(const s16x8*)(Ab_ +                                          \
          swz16(wr * 128 + (MIH) * 64 + mi * 16 + l15, lk * 16));              \
      a1_[mi] = *(const s16x8*)(Ab_ +                                          \
          swz16(wr * 128 + (MIH) * 64 + mi * 16 + l15, 64 + lk * 16));         \
    }                                                                          \
    s16x8 b00_ = *(const s16x8*)(Bb_ +                                         \
        swz16(wc * 64 + (NIH) * 32 + l15, lk * 16));                           \
    s16x8 b01_ = *(const s16x8*)(Bb_ +                                         \
        swz16(wc * 64 + (NIH) * 32 + 16 + l15, lk * 16));                      \
    s16x8 b10_ = *(const s16x8*)(Bb_ +                                         \
        swz16(wc * 64 + (NIH) * 32 + l15, 64 + lk * 16));                      \
    s16x8 b11_ = *(const s16x8*)(Bb_ +                                         \
        swz16(wc * 64 + (NIH) * 32 + 16 + l15, 64 + lk * 16));                 \
    if (more) STAGEU(U, t + 1);                                                \
    FENCE;                                                                     \
    __builtin_amdgcn_s_barrier();                                              \
    __builtin_amdgcn_s_setprio(1);                                             \
    _Pragma("unroll") for (int mi = 0; mi < 4; mi++) {                         \
      acc[(MIH) * 4 + mi][(NIH) * 2] =                                         \
          mfma16(a0_[mi], b00_, acc[(MIH) * 4 + mi][(NIH) * 2]);               \
      acc[(MIH) * 4 + mi][(NIH) * 2 + 1] =                                     \
          mfma16(a0_[mi], b01_, acc[(MIH) * 4 + mi][(NIH) * 2 + 1]);           \
    }                                                                          \
    _Pragma("unroll") for (int mi = 0; mi < 4; mi++) {                         \
      acc[(MIH) * 4 + mi][(NIH) * 2] =                                         \
          mfma16(a1_[mi], b10_, acc[(MIH) * 4 + mi][(NIH) * 2]);               \
      acc[(MIH) * 4 + mi][(NIH) * 2 + 1] =                                     \
          mfma16(a1_[mi], b11_, acc[(MIH) * 4 + mi][(NIH) * 2 + 1]);           \
    }                                                                          \
    __builtin_amdgcn_s_setprio(0);                                             \
  }

// ======== mlp1: H = gelu(X@Wg)*(X@Wu); 256x256xBK64, 8 waves, 8-phase =======
__global__ __launch_bounds__(512, 2) void k_mlp1(
    const unsigned short* __restrict__ xb, const unsigned short* __restrict__ wguT,
    const int* __restrict__ perm_tok, const int* __restrict__ offs,
    unsigned short* __restrict__ H) {
  extern __shared__ char lds[];  // [2][ A 32KB | B 32KB ] = 128 KB
  const int e = blockIdx.z;
  const int off = offs[e], cnt = offs[e + 1] - off;
  const int nb = blockIdx.x * 256;  // N' panel (N' = 8192)
  const unsigned short* wgu_e = wguT + (size_t)e * 2 * DDIM * FDIM;
  const int tid = threadIdx.x;
  const int lane = tid & 63;
  const int wid = tid >> 6;
  const int wr = wid >> 2, wc = wid & 3;  // 2M x 4N wave grid
  const int l15 = lane & 15, lk = lane >> 4;
  const int NT = DDIM / 64;

#pragma unroll 1
  for (int mt = blockIdx.y; mt * 256 < cnt; mt += 8) {
    const unsigned short* sp[4][2];
#pragma unroll
    for (int c = 0; c < 2; c++) {
      int r = wid * 16 + c * 8 + (lane >> 3);          // 0..127 within unit
      int k16 = (lane & 7) ^ (r & 7);                  // pre-swizzled k slot
      int glo = mt * 256 + r, ghi = mt * 256 + 128 + r;
      if (glo >= cnt) glo = cnt - 1;
      if (ghi >= cnt) ghi = cnt - 1;
      sp[0][c] = xb + (size_t)perm_tok[off + glo] * DDIM + k16 * 8;
      sp[1][c] = xb + (size_t)perm_tok[off + ghi] * DDIM + k16 * 8;
      sp[2][c] = wgu_e + (size_t)(nb + r) * DDIM + k16 * 8;
      sp[3][c] = wgu_e + (size_t)(nb + 128 + r) * DDIM + k16 * 8;
    }
    f32x4 acc[8][4];
#pragma unroll
    for (int mi = 0; mi < 8; mi++)
#pragma unroll
      for (int ni = 0; ni < 4; ni++) acc[mi][ni] = f32x4{0.f, 0.f, 0.f, 0.f};

    STAGEU(0, 0) STAGEU(1, 0) STAGEU(2, 0) STAGEU(3, 0)
    VMC(0);
    FENCE;
    __builtin_amdgcn_s_barrier();
    FENCE;
#pragma unroll 1
    for (int t = 0; t < NT; t++) {
      const int buf = t & 1;
      const bool more = (t + 1) < NT;
      PH(0, 0, 0)
      PH(0, 1, 1)
      PH(1, 0, 2)
      PH(1, 1, 3)
      VMC(0);
      FENCE;
      __builtin_amdgcn_s_barrier();
      FENCE;
    }

    // epilogue: ni even = gate, ni odd = up (same 16 H-cols)
#pragma unroll
    for (int am = 0; am < 8; am++) {
      int rb = wr * 128 + am * 16 + lk * 4;
#pragma unroll
      for (int j = 0; j < 4; j++) {
        int gm = mt * 256 + rb + j;
        if (gm < cnt) {
          unsigned short* hrow = H + (size_t)(off + gm) * FDIM;
#pragma unroll
          for (int ni = 0; ni < 4; ni += 2) {
            int jj = (nb >> 4) + wc * 4 + ni;
            int hc = ((jj >> 1) << 4) + l15;
            float g = acc[am][ni][j];
            float u = acc[am][ni + 1][j];
            float x3 = g * g * g;
            float gl = 0.5f * g * (1.0f + tanhf(0.7978845608f * (g + 0.044715f * x3)));
            hrow[hc] = bf16r(gl * u);
          }
        }
      }
    }
  }
}

// ======== mlp2: out += w * (He @ Wd), 256x256xBK64, 8 waves, 8-phase ========
__global__ __launch_bounds__(512, 2) void k_mlp2(
    const unsigned short* __restrict__ H, const unsigned short* __restrict__ wdT,
    const int* __restrict__ perm_tok, const float* __restrict__ perm_w,
    const int* __restrict__ offs, float* __restrict__ out) {
  extern __shared__ char lds[];
  const int e = blockIdx.z;
  const int off = offs[e], cnt = offs[e + 1] - off;
  const int nb = blockIdx.x * 256;
  const unsigned short* wd_e = wdT + (size_t)e * FDIM * DDIM;  // [n=D][k=F]
  const int tid = threadIdx.x;
  const int lane = tid & 63;
  const int wid = tid >> 6;
  const int wr = wid >> 2, wc = wid & 3;
  const int l15 = lane & 15, lk = lane >> 4;
  const int NT = FDIM / 64;

#pragma unroll 1
  for (int mt = blockIdx.y; mt * 256 < cnt; mt += 8) {
    const unsigned short* sp[4][2];
#pragma unroll
    for (int c = 0; c < 2; c++) {
      int r = wid * 16 + c * 8 + (lane >> 3);
      int k16 = (lane & 7) ^ (r & 7);
      int glo = mt * 256 + r, ghi = mt * 256 + 128 + r;
      if (glo >= cnt) glo = cnt - 1;
      if (ghi >= cnt) ghi = cnt - 1;
      sp[0][c] = H + (size_t)(off + glo) * FDIM + k16 * 8;
      sp[1][c] = H + (size_t)(off + ghi) * FDIM + k16 * 8;
      sp[2][c] = wd_e + (size_t)(nb + r) * FDIM + k16 * 8;
      sp[3][c] = wd_e + (size_t)(nb + 128 + r) * FDIM + k16 * 8;
    }
    f32x4 acc[8][4];
#pragma unroll
    for (int mi = 0; mi < 8; mi++)
#pragma unroll
      for (int ni = 0; ni < 4; ni++) acc[mi][ni] = f32x4{0.f, 0.f, 0.f, 0.f};

    STAGEU(0, 0) STAGEU(1, 0) STAGEU(2, 0) STAGEU(3, 0)
    VMC(0);
    FENCE;
    __builtin_amdgcn_s_barrier();
    FENCE;
#pragma unroll 1
    for (int t = 0; t < NT; t++) {
      const int buf = t & 1;
      const bool more = (t + 1) < NT;
      PH(0, 0, 0)
      PH(0, 1, 1)
      PH(1, 0, 2)
      PH(1, 1, 3)
      VMC(0);
      FENCE;
      __builtin_amdgcn_s_barrier();
      FENCE;
    }

#pragma unroll
    for (int am = 0; am < 8; am++) {
      int rb = wr * 128 + am * 16 + lk * 4;
#pragma unroll
      for (int j = 0; j < 4; j++) {
        int gm = mt * 256 + rb + j;
        if (gm < cnt) {
          int tok = perm_tok[off + gm];
          float w = perm_w[off + gm];
          float* orow = out + (size_t)tok * DDIM + nb + wc * 64 + l15;
#pragma unroll
          for (int ni = 0; ni < 4; ni++) atomicAdd(&orow[ni * 16], w * acc[am][ni][j]);
        }
      }
    }
  }
}

extern "C" void kernel_launch(void* const* d_in, const int* in_sizes, int n_in,
                              void* d_out, int out_size, void* d_ws, size_t ws_size,
                              hipStream_t stream) {
  const float* x = (const float*)d_in[0];
  const float* gw = (const float*)d_in[1];
  const float* wgate = (const float*)d_in[2];
  const float* wup = (const float*)d_in[3];
  const float* wdown = (const float*)d_in[4];
  float* out = (float*)d_out;

  const size_t XB_B = 33554432;                  // xb bf16 [8192][2048]
  const size_t H_B = 134217728;                  // H bf16 [16384][4096]
  const size_t WGU_B = 268435456;                // wguT bf16 [E][8192][2048]
  const size_t WD_B = 134217728;                 // wdT bf16 [E][2048][4096]

  char* ws = (char*)d_ws;
  unsigned short* xb = (unsigned short*)ws;
  unsigned short* H = (unsigned short*)(ws + XB_B);
  unsigned short* wguT = (unsigned short*)(ws + XB_B + H_B);
  unsigned short* wdT = (unsigned short*)(ws + XB_B + H_B + WGU_B);
  char* meta = ws + XB_B + H_B + WGU_B + WD_B;
  int* counts = (int*)(meta);
  int* offs = (int*)(meta + 64);
  int* cursor = (int*)(meta + 128);
  int* top_idx = (int*)(meta + 256);
  float* top_w = (float*)(meta + 256 + 65536);
  int* perm_tok = (int*)(meta + 256 + 131072);
  float* perm_w = (float*)(meta + 256 + 196608);

  (void)hipFuncSetAttribute((const void*)k_mlp1,
                            hipFuncAttributeMaxDynamicSharedMemorySize, 131072);
  (void)hipFuncSetAttribute((const void*)k_mlp2,
                            hipFuncAttributeMaxDynamicSharedMemorySize, 131072);

  (void)hipMemsetAsync(counts, 0, 64, stream);
  (void)hipMemsetAsync(d_out, 0, (size_t)TNUM * DDIM * 4, stream);
  k_router<<<TNUM / 4, 256, 0, stream>>>(x, gw, top_idx, top_w, counts);
  k_scan<<<1, 64, 0, stream>>>(counts, offs, cursor);
  k_scatter<<<TNUM / 256, 256, 0, stream>>>(top_idx, top_w, cursor, perm_tok, perm_w);
  k_cast<<<(TNUM * DDIM / 8) / 256, 256, 0, stream>>>(x, xb);
  k_convT<<<dim3(FDIM / 64, DDIM / 64, NEXP), 256, 0, stream>>>(wgate, wguT, DDIM, FDIM, 1);
  k_convT<<<dim3(FDIM / 64, DDIM / 64, NEXP), 256, 0, stream>>>(wup, wguT, DDIM, FDIM, 2);
  k_convT<<<dim3(DDIM / 64, FDIM / 64, NEXP), 256, 0, stream>>>(wdown, wdT, FDIM, DDIM, 0);
  k_mlp1<<<dim3(2 * FDIM / 256, 8, NEXP), 512, 131072, stream>>>(xb, wguT, perm_tok, offs, H);
  k_mlp2<<<dim3(DDIM / 256, 8, NEXP), 512, 131072, stream>>>(H, wdT, perm_tok, perm_w, offs, out);
}

// Round 11
// 1468.327 us; speedup vs baseline: 1.0982x; 1.0982x over previous
//
#include <hip/hip_runtime.h>
#include <hip/hip_bf16.h>
#include <cstdint>
#include <cstddef>

#define TNUM 8192
#define DDIM 2048
#define FDIM 4096
#define NEXP 8

typedef __attribute__((ext_vector_type(4))) float f32x4;
typedef __attribute__((ext_vector_type(4))) unsigned u32x4;
typedef __attribute__((ext_vector_type(8))) short s16x8;
typedef __attribute__((ext_vector_type(8))) __bf16 bf16x8v;

__device__ inline f32x4 mfma16(s16x8 a, s16x8 b, f32x4 c) {
  return __builtin_amdgcn_mfma_f32_16x16x32_bf16(
      __builtin_bit_cast(bf16x8v, a), __builtin_bit_cast(bf16x8v, b), c, 0, 0, 0);
}

__device__ inline unsigned short bf16r(float f) {
  union { float f; unsigned u; } x; x.f = f;
  unsigned r = x.u + 0x7fffu + ((x.u >> 16) & 1u);
  return (unsigned short)(r >> 16);
}

__device__ inline unsigned pk2(float a, float b) {
  __hip_bfloat162 h = __float22bfloat162_rn(make_float2(a, b));
  unsigned r;
  __builtin_memcpy(&r, &h, 4);
  return r;
}

typedef const __attribute__((address_space(1))) void* gp_t;
typedef __attribute__((address_space(3))) void* lp_t;
__device__ inline void gl16(const void* g, void* l) {
  __builtin_amdgcn_global_load_lds((gp_t)g, (lp_t)l, 16, 0, 0);
}

#define FENCE asm volatile("" ::: "memory")

// ---------------- router: fp64 logits, top-2 on logits, fp32 softmax values --
__global__ __launch_bounds__(256) void k_router(
    const float* __restrict__ x, const float* __restrict__ gw,
    int* __restrict__ top_idx, float* __restrict__ top_w, int* __restrict__ counts) {
  __shared__ float gwT[NEXP][DDIM];
  const int tid = threadIdx.x;
  for (int i = tid; i < NEXP * DDIM; i += 256) {
    int d = i >> 3, e = i & 7;
    gwT[e][d] = gw[i];
  }
  __syncthreads();
  const int lane = tid & 63;
  const int t = blockIdx.x * 4 + (tid >> 6);
  const float4* xr = (const float4*)(x + (size_t)t * DDIM);
  double acc[NEXP];
#pragma unroll
  for (int e = 0; e < NEXP; e++) acc[e] = 0.0;
  for (int d4 = lane; d4 < DDIM / 4; d4 += 64) {
    float4 xv = xr[d4];
#pragma unroll
    for (int e = 0; e < NEXP; e++) {
      float4 gv = *(const float4*)&gwT[e][d4 * 4];
      acc[e] += (double)xv.x * gv.x + (double)xv.y * gv.y +
                (double)xv.z * gv.z + (double)xv.w * gv.w;
    }
  }
#pragma unroll
  for (int e = 0; e < NEXP; e++) {
    double v = acc[e];
#pragma unroll
    for (int s = 32; s > 0; s >>= 1) v += __shfl_xor(v, s);
    acc[e] = v;
  }
  if (lane == 0) {
    int i0 = 0; double b0 = acc[0];
#pragma unroll
    for (int e = 1; e < NEXP; e++) if (acc[e] > b0) { b0 = acc[e]; i0 = e; }
    int i1 = (i0 == 0) ? 1 : 0; double b1 = acc[i1];
#pragma unroll
    for (int e = 0; e < NEXP; e++) {
      if (e == i0 || e == i1) continue;
      if (acc[e] > b1) { b1 = acc[e]; i1 = e; }
    }
    float lc[NEXP]; float mx = -1e30f;
#pragma unroll
    for (int e = 0; e < NEXP; e++) {
      lc[e] = tanhf((float)(acc[e] * (1.0 / 30.0))) * 30.0f;
      mx = lc[e] > mx ? lc[e] : mx;
    }
    float s = 0.0f;
#pragma unroll
    for (int e = 0; e < NEXP; e++) { lc[e] = expf(lc[e] - mx); s += lc[e]; }
    float inv = 1.0f / s;
    top_idx[t * 2] = i0; top_idx[t * 2 + 1] = i1;
    top_w[t * 2] = lc[i0] * inv; top_w[t * 2 + 1] = lc[i1] * inv;
    atomicAdd(&counts[i0], 1);
    atomicAdd(&counts[i1], 1);
  }
}

__global__ void k_scan(const int* __restrict__ counts, int* __restrict__ offs,
                       int* __restrict__ cursor) {
  if (threadIdx.x == 0) {
    int s = 0;
    for (int e = 0; e < NEXP; e++) { offs[e] = s; cursor[e] = s; s += counts[e]; }
    offs[NEXP] = s;
  }
}

__global__ void k_scatter(const int* __restrict__ top_idx, const float* __restrict__ top_w,
                          int* __restrict__ cursor, int* __restrict__ perm_tok,
                          float* __restrict__ perm_w) {
  int t = blockIdx.x * 256 + threadIdx.x;
#pragma unroll
  for (int k = 0; k < 2; k++) {
    int e = top_idx[t * 2 + k];
    int pos = atomicAdd(&cursor[e], 1);
    perm_tok[pos] = t;
    perm_w[pos] = top_w[t * 2 + k];
  }
}

__global__ void k_cast(const float* __restrict__ x, unsigned short* __restrict__ xb) {
  size_t i = ((size_t)blockIdx.x * 256 + threadIdx.x) * 8;
  f32x4 a = *(const f32x4*)(x + i);
  f32x4 b = *(const f32x4*)(x + i + 4);
  u32x4 v;
  v[0] = pk2(a[0], a[1]); v[1] = pk2(a[2], a[3]);
  v[2] = pk2(b[0], b[1]); v[3] = pk2(b[2], b[3]);
  *(u32x4*)(xb + i) = v;
}

// ---- one-shot: fp32 [E][K][N] -> bf16 [E][n'][K] transpose+convert ----------
// cmap=0: n'=n. cmap=1 (gate): n'=((n>>4)<<5)+(n&15). cmap=2 (up): +16.
__global__ __launch_bounds__(256) void k_convT(
    const float* __restrict__ src, unsigned short* __restrict__ dst,
    int K, int N, int cmap) {
  __shared__ char ct[8192];
  const int e = blockIdx.z;
  const float* src_e = src + (size_t)e * K * N;
  const int nout = cmap ? 2 * N : N;
  unsigned short* dst_e = dst + (size_t)e * nout * K;
  const int k0 = blockIdx.y * 64, n0 = blockIdx.x * 64;
  const int tid = threadIdx.x;
#pragma unroll
  for (int i = 0; i < 4; i++) {
    int idx = tid + i * 256;
    int kr = idx >> 4, f4 = idx & 15;
    f32x4 v = *(const f32x4*)(src_e + (size_t)(k0 + kr) * N + n0 + f4 * 4);
#pragma unroll
    for (int j = 0; j < 4; j++) {
      int n = f4 * 4 + j;
      *(unsigned short*)(ct + n * 128 + ((kr * 2) ^ ((n & 7) << 4))) = bf16r(v[j]);
    }
  }
  __syncthreads();
#pragma unroll
  for (int i = 0; i < 2; i++) {
    int s = tid + i * 256;
    int n = s >> 3, ks = s & 7;
    int gn = n0 + n;
    int cd = cmap ? (((gn >> 4) << 5) + (gn & 15) + (cmap == 2 ? 16 : 0)) : gn;
    s16x8 val = *(const s16x8*)(ct + n * 128 + ((ks * 16) ^ ((n & 7) << 4)));
    *(s16x8*)(dst_e + (size_t)cd * K + k0 + ks * 8) = val;
  }
}

// LDS (per 64KB buffer): A-kk0 | A-kk1 | B-kk0 | B-kk1, each 16KB =
// 256 rows x 64B, slot-swizzled: data(row, slot) = k-group slot^((row>>1)&3).
// Stage quarter (A or B, half KK) of K-tile TN into buf TN&1 (2 gl16/wave).
#define STG_A(KK, TN)                                                          \
  {                                                                            \
    char* d_ = lds + ((TN) & 1) * 65536 + (KK) * 16384 + wid * 2048;           \
    gl16(spA[0] + (size_t)(TN) * 128 + (KK) * 64, d_);                         \
    gl16(spA[1] + (size_t)(TN) * 128 + (KK) * 64, d_ + 1024);                  \
  }
#define STG_B(KK, TN)                                                          \
  {                                                                            \
    char* d_ = lds + ((TN) & 1) * 65536 + 32768 + (KK) * 16384 + wid * 2048;   \
    gl16(spB[0] + (size_t)(TN) * 128 + (KK) * 64, d_);                         \
    gl16(spB[1] + (size_t)(TN) * 128 + (KK) * 64, d_ + 1024);                  \
  }

#define VMC(N) asm volatile("s_waitcnt vmcnt(" #N ")" ::: "memory")

// Region KK of K-tile TN: ds-read a[8]+b[4] (kk=KK frags), issue the KK-pair
// stage of tile TN+1 (if MORE), MFMA 32 (setprio-wrapped halves).
#define RGN(KK, TN, MORE)                                                      \
  {                                                                            \
    char* Aq_ = lds + ((TN) & 1) * 65536 + (KK) * 16384;                       \
    char* Bq_ = Aq_ + 32768;                                                   \
    s16x8 a_[8];                                                               \
    _Pragma("unroll") for (int mi = 0; mi < 8; mi++)                           \
      a_[mi] = *(const s16x8*)(Aq_ + (wr * 128 + mi * 16 + l15) * 64 + sl16);  \
    s16x8 b0_ = *(const s16x8*)(Bq_ + (wc * 64 + l15) * 64 + sl16);            \
    s16x8 b1_ = *(const s16x8*)(Bq_ + (wc * 64 + 16 + l15) * 64 + sl16);       \
    if (MORE) { STG_A(KK, (TN) + 1); }                                         \
    __builtin_amdgcn_s_setprio(1);                                             \
    _Pragma("unroll") for (int mi = 0; mi < 8; mi++) {                         \
      acc[mi][0] = mfma16(a_[mi], b0_, acc[mi][0]);                            \
      acc[mi][1] = mfma16(a_[mi], b1_, acc[mi][1]);                            \
    }                                                                          \
    __builtin_amdgcn_s_setprio(0);                                             \
    s16x8 b2_ = *(const s16x8*)(Bq_ + (wc * 64 + 32 + l15) * 64 + sl16);       \
    s16x8 b3_ = *(const s16x8*)(Bq_ + (wc * 64 + 48 + l15) * 64 + sl16);       \
    if (MORE) { STG_B(KK, (TN) + 1); }                                         \
    __builtin_amdgcn_s_setprio(1);                                             \
    _Pragma("unroll") for (int mi = 0; mi < 8; mi++) {                         \
      acc[mi][2] = mfma16(a_[mi], b2_, acc[mi][2]);                            \
      acc[mi][3] = mfma16(a_[mi], b3_, acc[mi][3]);                            \
    }                                                                          \
    __builtin_amdgcn_s_setprio(0);                                             \
  }

// ======== mlp1: H = gelu(X@Wg)*(X@Wu); 256x256xBK64, 8 waves, counted T4 ====
__global__ __launch_bounds__(512, 2) void k_mlp1(
    const unsigned short* __restrict__ xb, const unsigned short* __restrict__ wguT,
    const int* __restrict__ perm_tok, const int* __restrict__ offs,
    unsigned short* __restrict__ H) {
  extern __shared__ char lds[];  // 2 x 64KB buffers
  const int e = blockIdx.z;
  const int off = offs[e], cnt = offs[e + 1] - off;
  const int nb = blockIdx.x * 256;  // N' panel (N' = 8192)
  const unsigned short* wgu_e = wguT + (size_t)e * 2 * DDIM * FDIM;
  const int tid = threadIdx.x;
  const int lane = tid & 63;
  const int wid = tid >> 6;
  const int wr = wid >> 2, wc = wid & 3;  // 2M x 4N wave grid
  const int l15 = lane & 15, lk = lane >> 4;
  const int sl16 = (lk ^ ((l15 >> 1) & 3)) * 16;           // read slot byte
  const int g16 = ((lane & 3) ^ ((lane >> 3) & 3)) * 16;   // source k-group byte
  const int NT = DDIM / 64;

#pragma unroll 1
  for (int mt = blockIdx.y; mt * 256 < cnt; mt += 8) {
    const char* spA[2];
    const char* spB[2];
#pragma unroll
    for (int c = 0; c < 2; c++) {
      int r = wid * 32 + c * 16 + (lane >> 2);             // 0..255
      int gm = mt * 256 + r;
      if (gm >= cnt) gm = cnt - 1;
      spA[c] = (const char*)(xb + (size_t)perm_tok[off + gm] * DDIM) + g16;
      spB[c] = (const char*)(wgu_e + (size_t)(nb + r) * DDIM) + g16;
    }
    f32x4 acc[8][4];
#pragma unroll
    for (int mi = 0; mi < 8; mi++)
#pragma unroll
      for (int ni = 0; ni < 4; ni++) acc[mi][ni] = f32x4{0.f, 0.f, 0.f, 0.f};

    // prologue: tile0, kk0 pair first (oldest), then kk1 pair
    STG_A(0, 0) STG_B(0, 0) STG_A(1, 0) STG_B(1, 0)
#pragma unroll 1
    for (int t = 0; t < NT; t++) {
      const bool more = (t + 1) < NT;
      // region0 reads kk0 pair of t; newest 4 outstanding = kk1 pair of t
      VMC(4);
      FENCE;
      __builtin_amdgcn_s_barrier();
      FENCE;
      RGN(0, t, more)
      // region1 reads kk1 pair of t; newest 4 = kk0 pair of t+1 (if staged)
      if (more) { VMC(4); } else { VMC(0); }
      FENCE;
      __builtin_amdgcn_s_barrier();
      FENCE;
      RGN(1, t, more)
    }

    // epilogue: ni even = gate, ni odd = up (same 16 H-cols)
#pragma unroll
    for (int am = 0; am < 8; am++) {
      int rb = wr * 128 + am * 16 + lk * 4;
#pragma unroll
      for (int j = 0; j < 4; j++) {
        int gm = mt * 256 + rb + j;
        if (gm < cnt) {
          unsigned short* hrow = H + (size_t)(off + gm) * FDIM;
#pragma unroll
          for (int ni = 0; ni < 4; ni += 2) {
            int jj = (nb >> 4) + wc * 4 + ni;
            int hc = ((jj >> 1) << 4) + l15;
            float g = acc[am][ni][j];
            float u = acc[am][ni + 1][j];
            float x3 = g * g * g;
            float gl = 0.5f * g * (1.0f + tanhf(0.7978845608f * (g + 0.044715f * x3)));
            hrow[hc] = bf16r(gl * u);
          }
        }
      }
    }
  }
}

// ======== mlp2: out += w * (He @ Wd), 256x256xBK64, 8 waves, counted T4 =====
__global__ __launch_bounds__(512, 2) void k_mlp2(
    const unsigned short* __restrict__ H, const unsigned short* __restrict__ wdT,
    const int* __restrict__ perm_tok, const float* __restrict__ perm_w,
    const int* __restrict__ offs, float* __restrict__ out) {
  extern __shared__ char lds[];
  const int e = blockIdx.z;
  const int off = offs[e], cnt = offs[e + 1] - off;
  const int nb = blockIdx.x * 256;
  const unsigned short* wd_e = wdT + (size_t)e * FDIM * DDIM;  // [n=D][k=F]
  const int tid = threadIdx.x;
  const int lane = tid & 63;
  const int wid = tid >> 6;
  const int wr = wid >> 2, wc = wid & 3;
  const int l15 = lane & 15, lk = lane >> 4;
  const int sl16 = (lk ^ ((l15 >> 1) & 3)) * 16;
  const int g16 = ((lane & 3) ^ ((lane >> 3) & 3)) * 16;
  const int NT = FDIM / 64;

#pragma unroll 1
  for (int mt = blockIdx.y; mt * 256 < cnt; mt += 8) {
    const char* spA[2];
    const char* spB[2];
#pragma unroll
    for (int c = 0; c < 2; c++) {
      int r = wid * 32 + c * 16 + (lane >> 2);
      int gm = mt * 256 + r;
      if (gm >= cnt) gm = cnt - 1;
      spA[c] = (const char*)(H + (size_t)(off + gm) * FDIM) + g16;
      spB[c] = (const char*)(wd_e + (size_t)(nb + r) * FDIM) + g16;
    }
    f32x4 acc[8][4];
#pragma unroll
    for (int mi = 0; mi < 8; mi++)
#pragma unroll
      for (int ni = 0; ni < 4; ni++) acc[mi][ni] = f32x4{0.f, 0.f, 0.f, 0.f};

    STG_A(0, 0) STG_B(0, 0) STG_A(1, 0) STG_B(1, 0)
#pragma unroll 1
    for (int t = 0; t < NT; t++) {
      const bool more = (t + 1) < NT;
      VMC(4);
      FENCE;
      __builtin_amdgcn_s_barrier();
      FENCE;
      RGN(0, t, more)
      if (more) { VMC(4); } else { VMC(0); }
      FENCE;
      __builtin_amdgcn_s_barrier();
      FENCE;
      RGN(1, t, more)
    }

#pragma unroll
    for (int am = 0; am < 8; am++) {
      int rb = wr * 128 + am * 16 + lk * 4;
#pragma unroll
      for (int j = 0; j < 4; j++) {
        int gm = mt * 256 + rb + j;
        if (gm < cnt) {
          int tok = perm_tok[off + gm];
          float w = perm_w[off + gm];
          float* orow = out + (size_t)tok * DDIM + nb + wc * 64 + l15;
#pragma unroll
          for (int ni = 0; ni < 4; ni++) atomicAdd(&orow[ni * 16], w * acc[am][ni][j]);
        }
      }
    }
  }
}

extern "C" void kernel_launch(void* const* d_in, const int* in_sizes, int n_in,
                              void* d_out, int out_size, void* d_ws, size_t ws_size,
                              hipStream_t stream) {
  const float* x = (const float*)d_in[0];
  const float* gw = (const float*)d_in[1];
  const float* wgate = (const float*)d_in[2];
  const float* wup = (const float*)d_in[3];
  const float* wdown = (const float*)d_in[4];
  float* out = (float*)d_out;

  const size_t XB_B = 33554432;                  // xb bf16 [8192][2048]
  const size_t H_B = 134217728;                  // H bf16 [16384][4096]
  const size_t WGU_B = 268435456;                // wguT bf16 [E][8192][2048]
  const size_t WD_B = 134217728;                 // wdT bf16 [E][2048][4096]

  char* ws = (char*)d_ws;
  unsigned short* xb = (unsigned short*)ws;
  unsigned short* H = (unsigned short*)(ws + XB_B);
  unsigned short* wguT = (unsigned short*)(ws + XB_B + H_B);
  unsigned short* wdT = (unsigned short*)(ws + XB_B + H_B + WGU_B);
  char* meta = ws + XB_B + H_B + WGU_B + WD_B;
  int* counts = (int*)(meta);
  int* offs = (int*)(meta + 64);
  int* cursor = (int*)(meta + 128);
  int* top_idx = (int*)(meta + 256);
  float* top_w = (float*)(meta + 256 + 65536);
  int* perm_tok = (int*)(meta + 256 + 131072);
  float* perm_w = (float*)(meta + 256 + 196608);

  (void)hipFuncSetAttribute((const void*)k_mlp1,
                            hipFuncAttributeMaxDynamicSharedMemorySize, 131072);
  (void)hipFuncSetAttribute((const void*)k_mlp2,
                            hipFuncAttributeMaxDynamicSharedMemorySize, 131072);

  (void)hipMemsetAsync(counts, 0, 64, stream);
  (void)hipMemsetAsync(d_out, 0, (size_t)TNUM * DDIM * 4, stream);
  k_router<<<TNUM / 4, 256, 0, stream>>>(x, gw, top_idx, top_w, counts);
  k_scan<<<1, 64, 0, stream>>>(counts, offs, cursor);
  k_scatter<<<TNUM / 256, 256, 0, stream>>>(top_idx, top_w, cursor, perm_tok, perm_w);
  k_cast<<<(TNUM * DDIM / 8) / 256, 256, 0, stream>>>(x, xb);
  k_convT<<<dim3(FDIM / 64, DDIM / 64, NEXP), 256, 0, stream>>>(wgate, wguT, DDIM, FDIM, 1);
  k_convT<<<dim3(FDIM / 64, DDIM / 64, NEXP), 256, 0, stream>>>(wup, wguT, DDIM, FDIM, 2);
  k_convT<<<dim3(DDIM / 64, FDIM / 64, NEXP), 256, 0, stream>>>(wdown, wdT, FDIM, DDIM, 0);
  k_mlp1<<<dim3(2 * FDIM / 256, 8, NEXP), 512, 131072, stream>>>(xb, wguT, perm_tok, offs, H);
  k_mlp2<<<dim3(DDIM / 256, 8, NEXP), 512, 131072, stream>>>(H, wdT, perm_tok, perm_w, offs, out);
}